// Round 1
// baseline (652.323 us; speedup 1.0000x reference)
//
#include <hip/hip_runtime.h>
#include <stdint.h>

// ---- problem constants ----
#define Z_LEV   34
#define N_CELL  (512 * 1024)            // H*W = 524288
#define NCOL    544                     // 2 matrices * 8 etas * 34 z
#define KPAD    104                     // 103 features padded to 104
#define WROW_BYTES 208                  // KPAD * 2 bytes (bf16)
#define BM      128                     // cells per tile
#define NTILES  (N_CELL / BM)           // 4096
#define NBLOCKS 256
#define THREADS 512

// ---- LDS layout (bytes) ----
#define LDS_W        0
#define LDS_W_SZ     (NCOL * WROW_BYTES)        // 113152
#define DUMP_STRIDE  548                        // floats; +4 pad breaks bank conflicts
#define LDS_DUMP     (LDS_W + LDS_W_SZ)
#define LDS_DUMP_SZ  (16 * DUMP_STRIDE * 4)     // 35072
#define LDS_BIAS     (LDS_DUMP + LDS_DUMP_SZ)
#define LDS_BIAS_SZ  (NCOL * 4)                 // 2176
#define LDS_ETA      (LDS_BIAS + LDS_BIAS_SZ)
#define LDS_ETA_SZ   (BM * 4)                   // 512
#define LDS_TOTAL    (LDS_ETA + LDS_ETA_SZ)     // 150912

typedef __attribute__((ext_vector_type(8))) short bf16x8;   // 8 bf16 = 4 VGPRs
typedef __attribute__((ext_vector_type(4))) float f32x4;
typedef __attribute__((ext_vector_type(4))) unsigned int u32x4;

__device__ __forceinline__ unsigned short f2bf(float f) {
  unsigned u = __float_as_uint(f);
  unsigned r = u + 0x7FFFu + ((u >> 16) & 1u);   // RNE
  return (unsigned short)(r >> 16);
}

__device__ __forceinline__ const float* feat_ptr(
    int f, const float* qtp, const float* slp, const float* sst,
    const float* qt, const float* sli, const float* sol) {
  // feature order: qt_pred[0:15], sli_pred[0:18], sst, qt[0:34], sli[0:34], solin
  const float* p;
  if (f < 15)       p = qtp + (size_t)f * N_CELL;
  else if (f < 33)  p = slp + (size_t)(f - 15) * N_CELL;
  else if (f == 33) p = sst;
  else if (f < 68)  p = qt + (size_t)(f - 34) * N_CELL;
  else if (f < 102) p = sli + (size_t)(f - 68) * N_CELL;
  else              p = sol;     // f == 102 (and clamped garbage k>=103)
  return p;
}

// Pack both weight matrices into ws as bf16 W[col][k]:
//   col = mat*272 + e*34 + z, k = feature (zero for k >= 103)
__global__ void prep_w_kernel(const float* __restrict__ wq,
                              const float* __restrict__ wsl,
                              unsigned short* __restrict__ Wp) {
  int idx = blockIdx.x * blockDim.x + threadIdx.x;
  if (idx >= NCOL * KPAD) return;
  int col = idx / KPAD;
  int k   = idx - col * KPAD;
  int mat = (col >= 272) ? 1 : 0;
  int cc  = col - mat * 272;
  int e = cc / 34, z = cc - e * 34;
  float v = 0.f;
  if (k < 103) {
    const float* w = mat ? wsl : wq;          // [8][103][34]
    v = w[((size_t)e * 103 + k) * 34 + z];
  }
  Wp[idx] = f2bf(v);
}

__global__ __launch_bounds__(THREADS, 2) void ssm_kernel(
    const float* __restrict__ qtp, const float* __restrict__ slp,
    const float* __restrict__ sst, const float* __restrict__ qt,
    const float* __restrict__ sli, const float* __restrict__ sol,
    const float* __restrict__ bq,  const float* __restrict__ bs,
    const int* __restrict__ eta,   const unsigned short* __restrict__ Wp,
    float* __restrict__ out) {
  extern __shared__ char smem[];
  unsigned short* Wl = (unsigned short*)(smem + LDS_W);
  float* dumpF = (float*)(smem + LDS_DUMP);
  float* biasL = (float*)(smem + LDS_BIAS);
  int*   etaL  = (int*)(smem + LDS_ETA);

  const int tid = threadIdx.x;

  // ---- stage W (persistent across the whole block lifetime) ----
  {
    const u32x4* src = (const u32x4*)Wp;
    u32x4* dst = (u32x4*)Wl;
    for (int i = tid; i < LDS_W_SZ / 16; i += THREADS) dst[i] = src[i];
  }
  for (int i = tid; i < NCOL; i += THREADS)
    biasL[i] = (i < 272) ? bq[i] : bs[i - 272];
  __syncthreads();

  const int w     = tid >> 6;       // wave 0..7
  const int lane  = tid & 63;
  const int g     = lane >> 4;      // k-group 0..3
  const int c16   = lane & 15;
  const int mpair = w >> 1;         // row-pair 0..3 (rows mpair*32 .. +31)
  const int nhalf = w & 1;          // column half (0: cols 0..271, 1: 272..543)

  const f32x4 zero4 = {0.f, 0.f, 0.f, 0.f};
  const bf16x8 zero8 = {0, 0, 0, 0, 0, 0, 0, 0};

  for (int tile = blockIdx.x; tile < NTILES; tile += gridDim.x) {
    const int tbase = tile * BM;

    if (tid < BM) etaL[tid] = eta[tbase + tid];   // visibility covered by the
                                                  // first epilogue barrier
    f32x4 acc0[17], acc1[17];
#pragma unroll
    for (int nt = 0; nt < 17; ++nt) { acc0[nt] = zero4; acc1[nt] = zero4; }

    const int cell0 = tbase + mpair * 32 + c16;   // A row (m-tile 2*mpair)
    const int cell1 = cell0 + 16;                 // A row (m-tile 2*mpair+1)

    // ---- full k-steps: k = 0..95 ----
#pragma unroll
    for (int ks = 0; ks < 3; ++ks) {
      bf16x8 A0, A1;
#pragma unroll
      for (int j = 0; j < 8; ++j) {
        int f = ks * 32 + g * 8 + j;
        const float* p = feat_ptr(f, qtp, slp, sst, qt, sli, sol);
        A0[j] = (short)f2bf(p[cell0]);
        A1[j] = (short)f2bf(p[cell1]);
      }
#pragma unroll
      for (int nt = 0; nt < 17; ++nt) {
        const int col = nhalf * 272 + nt * 16 + c16;
        const bf16x8 B = *(const bf16x8*)((const char*)Wl +
                           (size_t)col * WROW_BYTES + (size_t)(ks * 64 + g * 16));
        acc0[nt] = __builtin_amdgcn_mfma_f32_16x16x32_bf16(A0, B, acc0[nt], 0, 0, 0);
        acc1[nt] = __builtin_amdgcn_mfma_f32_16x16x32_bf16(A1, B, acc1[nt], 0, 0, 0);
      }
    }

    // ---- partial k-step: k = 96..103 live only in group 0 (A=0 elsewhere,
    //      W rows zero-padded at k=103) ----
    {
      bf16x8 A0 = zero8, A1 = zero8;
      if (g == 0) {
#pragma unroll
        for (int j = 0; j < 8; ++j) {
          int f = 96 + j; if (f > 102) f = 102;   // k=103: any finite value, B=0
          const float* p = feat_ptr(f, qtp, slp, sst, qt, sli, sol);
          A0[j] = (short)f2bf(p[cell0]);
          A1[j] = (short)f2bf(p[cell1]);
        }
      }
#pragma unroll
      for (int nt = 0; nt < 17; ++nt) {
        const int col = nhalf * 272 + nt * 16 + c16;
        const bf16x8 B = *(const bf16x8*)((const char*)Wl +
                           (size_t)col * WROW_BYTES + 192);
        acc0[nt] = __builtin_amdgcn_mfma_f32_16x16x32_bf16(A0, B, acc0[nt], 0, 0, 0);
        acc1[nt] = __builtin_amdgcn_mfma_f32_16x16x32_bf16(A1, B, acc1[nt], 0, 0, 0);
      }
    }

    // ---- epilogue: per 16-row m-tile, dump acc to LDS, select eta cols ----
    for (int mt = 0; mt < 8; ++mt) {
      if (mpair == (mt >> 1)) {
        if ((mt & 1) == 0) {
#pragma unroll
          for (int nt = 0; nt < 17; ++nt)
#pragma unroll
            for (int r = 0; r < 4; ++r)
              dumpF[(g * 4 + r) * DUMP_STRIDE + (nhalf * 272 + nt * 16 + c16)] =
                  acc0[nt][r];
        } else {
#pragma unroll
          for (int nt = 0; nt < 17; ++nt)
#pragma unroll
            for (int r = 0; r < 4; ++r)
              dumpF[(g * 4 + r) * DUMP_STRIDE + (nhalf * 272 + nt * 16 + c16)] =
                  acc1[nt][r];
        }
      }
      __syncthreads();

      for (int e = tid; e < 16 * 68; e += THREADS) {
        int zo = e >> 4, c = e & 15;
        int mat = (zo >= 34) ? 1 : 0;
        int z = zo - mat * 34;
        int gcell = tbase + mt * 16 + c;
        int ec = etaL[mt * 16 + c];
        int col = mat * 272 + ec * 34 + z;
        float res  = dumpF[c * DUMP_STRIDE + col];
        float bias = biasL[col];
        const float* pp = mat ? slp : qtp;
        float pred = pp[(size_t)z * N_CELL + gcell];
        out[(size_t)(mat * 34 + z) * N_CELL + gcell] = pred + res + bias;
      }
      __syncthreads();
    }
  }
}

extern "C" void kernel_launch(void* const* d_in, const int* in_sizes, int n_in,
                              void* d_out, int out_size, void* d_ws, size_t ws_size,
                              hipStream_t stream) {
  const float* qtp = (const float*)d_in[0];
  const float* slp = (const float*)d_in[1];
  const float* sst = (const float*)d_in[2];
  const float* qt  = (const float*)d_in[3];
  const float* sli = (const float*)d_in[4];
  const float* sol = (const float*)d_in[5];
  const float* wq  = (const float*)d_in[6];
  const float* bq  = (const float*)d_in[7];
  const float* wsl = (const float*)d_in[8];
  const float* bs  = (const float*)d_in[9];
  const int*   eta = (const int*)d_in[10];
  float* out = (float*)d_out;
  unsigned short* Wp = (unsigned short*)d_ws;   // needs 113152 B

  prep_w_kernel<<<(NCOL * KPAD + 255) / 256, 256, 0, stream>>>(wq, wsl, Wp);

  (void)hipFuncSetAttribute((const void*)ssm_kernel,
                            hipFuncAttributeMaxDynamicSharedMemorySize, LDS_TOTAL);
  ssm_kernel<<<NBLOCKS, THREADS, LDS_TOTAL, stream>>>(
      qtp, slp, sst, qt, sli, sol, bq, bs, eta, Wp, out);
}